// Round 2
// baseline (2189.383 us; speedup 1.0000x reference)
//
#include <hip/hip_runtime.h>

#ifndef M_PI
#define M_PI 3.14159265358979323846
#endif

#define TF 16
#define NU (TF * 257)

// ---------------- precomputed operators (recomputed every launch; deterministic) ----------------
__device__ double g_tblc[512];
__device__ double g_tbls[512];
__device__ double g_CFP[49 * 512];   // cft(511,48,+0.42): [j 0..48][n 0..511]
__device__ double g_CFC[512 * 25];   // cft(24,511,-0.42): [n 0..511][m 0..24]
__device__ float2 g_g2[257 * 49];    // (Gc, Gs) [k][j]
__device__ float2 g_M2[24 * 257];    // (Mcr, Mci) [m][k]

// systolic wavefront computation of the two cft recurrence matrices (fp64), plus trig tables
__global__ void prepA() {
  const int tid = threadIdx.x;
  const int w = tid >> 6;
  const int lane = tid & 63;
  if (w == 0) {
    // CFP: rows i = lane (0..48), iterate j; A[i][j] = A[i-1][j-1] + a*(A[i][j-1] - A[i-1][j])
    const double a = 0.42, beta = 1.0 - a * a;
    double v1 = 0.0, v2 = 0.0;
    for (int s = 0; s < 49 + 512; ++s) {
      double up1 = __shfl_up(v1, 1);
      double up2 = __shfl_up(v2, 1);
      int j = s - lane;
      double val;
      if (lane == 0)      val = (j == 0) ? 1.0 : 0.0;
      else if (lane == 1) val = (j < 1) ? 0.0 : ((j == 1) ? beta : v1 * a);
      else                val = (j < 1) ? 0.0 : (up2 + a * (v1 - up1));
      if (lane < 49 && j >= 0 && j < 512) g_CFP[lane * 512 + j] = val;
      v2 = v1; v1 = val;
    }
  } else if (w == 1) {
    // CFC: cols j = lane (0..24), iterate rows i
    const double a = -0.42, beta = 1.0 - a * a;
    double c1 = (lane >= 1) ? pow(a, (double)(lane - 1)) * beta : 0.0;
    double v1 = 0.0, v2 = 0.0;
    for (int s = 0; s < 512 + 25; ++s) {
      double up1 = __shfl_up(v1, 1);
      double up2 = __shfl_up(v2, 1);
      int i = s - lane;
      double val;
      if (lane == 0) val = (i == 0) ? 1.0 : 0.0;
      else if (i < 1) val = 0.0;
      else if (i == 1) val = c1;
      else val = up2 + a * (up1 - v1);
      if (lane < 25 && i >= 0 && i < 512) g_CFC[i * 25 + lane] = val;
      v2 = v1; v1 = val;
    }
  }
  for (int t = tid; t < 512; t += blockDim.x) {
    double th = (2.0 * M_PI * (double)t) / 512.0;
    g_tblc[t] = cos(th);
    g_tbls[t] = sin(th);
  }
}

// Gc[k][j] = (c_k/512) * sum_n cos(2pi k n/512) CFP[j][n];  Gs = -(2/512) * sum_n sin(...) CFP[j][n]
__global__ void prepB() {
  int idx = blockIdx.x * 256 + threadIdx.x;
  if (idx >= 257 * 49) return;
  int k = idx / 49, j = idx - k * 49;
  double ac = 0.0, as = 0.0;
  for (int n = 0; n < 512; ++n) {
    double wv = g_CFP[j * 512 + n];
    int t = (k * n) & 511;
    ac += g_tblc[t] * wv;
    as += g_tbls[t] * wv;
  }
  bool edge = (k == 0) || (k == 256);
  float gc = (float)((edge ? 1.0 : 2.0) / 512.0 * ac);
  float gs = edge ? 0.f : (float)(-2.0 / 512.0 * as);
  g_g2[idx] = make_float2(gc, gs);
}

// Mcr[m][k] = sum_n CFC[n][m+1] cos(2pi k n/512);  Mci = -sum_n CFC[n][m+1] sin(...)
__global__ void prepC() {
  int idx = blockIdx.x * 256 + threadIdx.x;
  if (idx >= 24 * 257) return;
  int m = idx / 257, k = idx - m * 257;
  double ar = 0.0, ai = 0.0;
  for (int n = 0; n < 512; ++n) {
    double wv = g_CFC[n * 25 + (m + 1)];
    int t = (k * n) & 511;
    ar += g_tblc[t] * wv;
    ai -= g_tbls[t] * wv;
  }
  g_M2[m * 257 + k] = make_float2((float)ar, (float)ai);
}

// ---------------- register-resident 24x24 GE (pivotless; system is SPD-like), 2 frames/wave ----------------
__device__ __forceinline__ float solve25(float (&own)[25], int base, int row) {
#pragma unroll
  for (int c = 0; c < 24; ++c) {
    float piv = __shfl(own[c], base + c, 64);
    float factor = own[c] / piv;
    bool act = (row > c) && (row < 24);
#pragma unroll
    for (int j = c + 1; j <= 24; ++j) {
      float pr = __shfl(own[j], base + c, 64);
      if (act) own[j] = fmaf(-factor, pr, own[j]);
    }
  }
  float sol = 0.f, acc = 0.f;
#pragma unroll
  for (int c = 23; c >= 0; --c) {
    float num = own[24] - acc;
    float xc = __shfl(num / own[c], base + c, 64);
    if (row == c) sol = xc;
    if (row < c) acc = fmaf(own[c], xc, acc);
  }
  return sol;
}

__global__ __launch_bounds__(256) void mgc_main(const float* __restrict__ xg,
                                                float* __restrict__ outg,
                                                int T) {
  __shared__ __align__(16) float xs[TF * 257];
  __shared__ __align__(16) float U[2 * NU];      // Xr | Yi spectra; also chain scratch
  __shared__ __align__(16) float pqr[TF][123];   // p[0..48] q[49..97] r[98..122]
  __shared__ __align__(16) float b1s[24][TF];
  __shared__ float b0s[TF];
  __shared__ float wfin[TF][26];

  const int tid = threadIdx.x;
  const long fbase = (long)blockIdx.x * TF;
  const long NTOT = (long)T * 257;

  { // load x tile (16 frames, contiguous)
    const float* src = xg + fbase * 257;
    for (int i = tid; i < TF * 257; i += 256) {
      long gi = fbase * 257 + i;
      xs[i] = (gi < NTOT) ? src[i] : 0.1f;
    }
  }
  __syncthreads();

  const int fP = tid >> 4;      // contraction frame
  const int jg = tid & 15;      // contraction output group
  const int lane = tid & 63;
  const int wv = tid >> 6;
  const int sbase = lane & 32;
  const int row = lane & 31;

  // ---- stage A: p0 = x @ Gc ----
  {
    float aP0 = 0.f, aP1 = 0.f, aP2 = 0.f, aP3 = 0.f;
    const float* xf = xs + fP * 257;
    for (int k = 0; k < 257; ++k) {
      float zp = xf[k];
      const float2* gr = g_g2 + k * 49;
      aP0 = fmaf(zp, gr[jg].x, aP0);
      aP1 = fmaf(zp, gr[jg + 16].x, aP1);
      aP2 = fmaf(zp, gr[jg + 32].x, aP2);
      if (jg == 0) aP3 = fmaf(zp, gr[48].x, aP3);
    }
    pqr[fP][jg] = aP0; pqr[fP][jg + 16] = aP1; pqr[fP][jg + 32] = aP2;
    if (jg == 0) pqr[fP][48] = aP3;
    pqr[fP][98 + jg] = aP0;                 // r = p0[:25]
    if (jg < 9) pqr[fP][98 + 16 + jg] = aP1;
  }
  __syncthreads();

  // ---- stage A: p = p0 @ PT_T (in place, two-step) ----
  {
    float pv[4];
#pragma unroll
    for (int it = 0; it < 4; ++it) {
      int idx = tid + it * 256;
      if (idx < TF * 49) {
        int f = idx / 49, j = idx - f * 49;
        float a = pqr[f][j];
        float b = (j < 48) ? pqr[f][j + 1] : 0.f;
        pv[it] = (j == 0) ? fmaf(0.84f, b, 0.8236f * a)
               : (j == 48) ? 1.42f * a
               : fmaf(0.42f, b, a);
      }
    }
    __syncthreads();
#pragma unroll
    for (int it = 0; it < 4; ++it) {
      int idx = tid + it * 256;
      if (idx < TF * 49) {
        int f = idx / 49, j = idx - f * 49;
        pqr[f][j] = pv[it];
      }
    }
  }
  __syncthreads();

  // ---- stage A solve: Toeplitz(p') b1 = r[1:] ----
#pragma unroll 1
  for (int pass = 0; pass < 2; ++pass) {
    int fs = 2 * wv + ((lane >= 32) ? 1 : 0) + 8 * pass;
    float own[25];
#pragma unroll
    for (int j = 0; j < 25; ++j) own[j] = 1.f;
    if (row < 24) {
#pragma unroll
      for (int j = 0; j < 24; ++j) {
        int d = (row > j) ? (row - j) : (j - row);
        own[j] = pqr[fs][d];
      }
      own[24] = pqr[fs][99 + row];
    }
    float sol = solve25(own, sbase, row);
    if (row < 24) b1s[row][fs] = sol;
  }
  __syncthreads();

  // ---- stage A chain: ignorm/B2MC/gnorm/gc2gc/ignorm/MC2B/gnorm (1 thread / frame) ----
  if (tid < TF) {
    const int f = tid;
    float* c1 = U + f * 32;
    float* c2 = U + TF * 32 + f * 32;
    float s = 0.f;
    for (int m = 0; m < 24; ++m) s = fmaf(pqr[f][99 + m], b1s[m][f], s);
    float eps = pqr[f][98] - s;
    float K = 1.f / sqrtf(eps);               // 1/b0
    c2[0] = 1.f - K;                          // ignorm(b,-1)
    for (int i = 1; i <= 24; ++i) c2[i] = b1s[i - 1][f] * K;
    for (int j = 0; j < 24; ++j) c1[j] = fmaf(0.42f, c2[j + 1], c2[j]);  // @B2MC_T
    c1[24] = c2[24];
    float z = 1.f - c1[0];                    // gnorm(c,-1)
    float iz = 1.f / z;
    c1[0] = iz;
    for (int i = 1; i <= 24; ++i) c1[i] *= iz;
    c2[0] = c1[0]; c2[1] = c1[1];             // gc2gc(-1 -> -0.5)
    for (int i = 2; i <= 24; ++i) {
      float s2 = 0.f, s1 = 0.f;
      for (int k = 1; k < i; ++k) {
        float cc = c1[k] * c2[i - k];
        s2 += (float)k * cc;
        s1 += (float)(i - k) * cc;
      }
      c2[i] = c1[i] + (-0.5f * s2 + s1) / (float)i;
    }
    float K2 = 1.f / sqrtf(c2[0]);            // ignorm(c2, -0.5)
    c2[0] = 2.f * (1.f - K2);
    for (int i = 1; i <= 24; ++i) c2[i] *= K2;
    c1[24] = c2[24];                          // @MC2B_T (backward)
    for (int j = 23; j >= 0; --j) c1[j] = fmaf(-0.42f, c1[j + 1], c2[j]);
    float z2 = 1.f - 0.5f * c1[0];            // gnorm(v,-0.5)[1:]
    float iz2 = 1.f / z2;
    for (int m = 0; m < 24; ++m) b1s[m][f] = c1[m + 1] * iz2;
  }
  __syncthreads();

  // ---- 6 Newton iterations ----
#pragma unroll 1
  for (int itn = 0; itn < 6; ++itn) {
    // P1: Xr/Yi spectra, 16-frame register blocking
    for (int k = tid; k < 257; k += 256) {
      float cr[TF], ci[TF];
#pragma unroll
      for (int f = 0; f < TF; ++f) { cr[f] = 0.f; ci[f] = 0.f; }
#pragma unroll 4
      for (int m = 0; m < 24; ++m) {
        float2 mm = g_M2[m * 257 + k];
        const float4* bp = (const float4*)(&b1s[m][0]);
        float4 b0v = bp[0], b1v = bp[1], b2v = bp[2], b3v = bp[3];
        float bf[TF] = {b0v.x, b0v.y, b0v.z, b0v.w, b1v.x, b1v.y, b1v.z, b1v.w,
                        b2v.x, b2v.y, b2v.z, b2v.w, b3v.x, b3v.y, b3v.z, b3v.w};
#pragma unroll
        for (int f = 0; f < TF; ++f) {
          cr[f] = fmaf(bf[f], mm.x, cr[f]);
          ci[f] = fmaf(bf[f], mm.y, ci[f]);
        }
      }
#pragma unroll
      for (int f = 0; f < TF; ++f) {
        U[f * 257 + k] = fmaf(-0.5f, cr[f], 1.f);  // Xr = 1 + g*Cr
        U[NU + f * 257 + k] = -0.5f * ci[f];       // Yi = g*Ci
      }
    }
    __syncthreads();

    // P2: 5-channel contraction against Gc/Gs (ps = x*D, qs = x for gamma = -1/2)
    {
      float aP0 = 0, aP1 = 0, aP2 = 0, aP3 = 0, aQ0 = 0, aQ1 = 0, aQ2 = 0, aQ3 = 0, aR0 = 0, aR1 = 0;
      const float* xf = xs + fP * 257;
      const float* Xrp = U + fP * 257;
      const float* Yip = U + NU + fP * 257;
      for (int k = 0; k < 257; ++k) {
        float xv = xf[k];
        float Xr = Xrp[k], Yi = Yip[k];
        float Xr2 = Xr * Xr, Yi2 = Yi * Yi;
        float D = Xr2 + Yi2;
        float xD = xv * D;
        float zqr = xv * (Xr2 - Yi2);
        float zqi = 2.f * xv * Xr * Yi;
        float zrr = xD * Xr;
        float zri = xD * Yi;
        const float2* gr = g_g2 + k * 49;
        float2 g0 = gr[jg];
        float2 g1 = gr[jg + 16];
        float2 g2v = gr[jg + 32];
        aP0 = fmaf(xD, g0.x, aP0);
        aQ0 = fmaf(zqr, g0.x, fmaf(zqi, g0.y, aQ0));
        aR0 = fmaf(zrr, g0.x, fmaf(zri, g0.y, aR0));
        aP1 = fmaf(xD, g1.x, aP1);
        aQ1 = fmaf(zqr, g1.x, fmaf(zqi, g1.y, aQ1));
        if (jg < 9) aR1 = fmaf(zrr, g1.x, fmaf(zri, g1.y, aR1));
        aP2 = fmaf(xD, g2v.x, aP2);
        aQ2 = fmaf(zqr, g2v.x, fmaf(zqi, g2v.y, aQ2));
        if (jg == 0) {
          float2 g3 = gr[48];
          aP3 = fmaf(xD, g3.x, aP3);
          aQ3 = fmaf(zqr, g3.x, fmaf(zqi, g3.y, aQ3));
        }
      }
      pqr[fP][jg] = aP0;      pqr[fP][jg + 16] = aP1;      pqr[fP][jg + 32] = aP2;
      pqr[fP][49 + jg] = aQ0; pqr[fP][49 + jg + 16] = aQ1; pqr[fP][49 + jg + 32] = aQ2;
      pqr[fP][98 + jg] = aR0;
      if (jg < 9) pqr[fP][98 + 16 + jg] = aR1;
      if (jg == 0) { pqr[fP][48] = aP3; pqr[fP][49 + 48] = aQ3; }
    }
    __syncthreads();

    // P3: sparse PT/QT transforms (in place) + eps (pre-update b1)
    {
      float pv[4], qv[4];
#pragma unroll
      for (int it = 0; it < 4; ++it) {
        int idx = tid + it * 256;
        if (idx < TF * 49) {
          int f = idx / 49, j = idx - f * 49;
          float pa = pqr[f][j];
          float pb = (j < 48) ? pqr[f][j + 1] : 0.f;
          pv[it] = (j == 0) ? fmaf(0.84f, pb, 0.8236f * pa)
                 : (j == 48) ? 1.42f * pa
                 : fmaf(0.42f, pb, pa);
          float qa = pqr[f][49 + j];
          float qb = (j >= 1) ? pqr[f][49 + j - 1] : 0.f;
          qv[it] = (j == 0) ? qa
                 : (j == 1) ? 1.42f * qa
                 : fmaf(0.42f, qb, qa);
        }
      }
      __syncthreads();
#pragma unroll
      for (int it = 0; it < 4; ++it) {
        int idx = tid + it * 256;
        if (idx < TF * 49) {
          int f = idx / 49, j = idx - f * 49;
          pqr[f][j] = pv[it];
          pqr[f][49 + j] = qv[it];
        }
      }
      if (tid < TF) {
        const int f = tid;
        float s = 0.f;
        for (int m = 0; m < 24; ++m) s = fmaf(pqr[f][99 + m], b1s[m][f], s);
        b0s[f] = sqrtf(pqr[f][98] - 0.5f * s);
      }
    }
    __syncthreads();

    // P4: (R + Q) d = r[1:], b1 += d
#pragma unroll 1
    for (int pass = 0; pass < 2; ++pass) {
      int fs = 2 * wv + ((lane >= 32) ? 1 : 0) + 8 * pass;
      float own[25];
#pragma unroll
      for (int j = 0; j < 25; ++j) own[j] = 1.f;
      if (row < 24) {
#pragma unroll
        for (int j = 0; j < 24; ++j) {
          int d = (row > j) ? (row - j) : (j - row);
          own[j] = pqr[fs][d] + 0.5f * pqr[fs][49 + 2 + row + j];
        }
        own[24] = pqr[fs][99 + row];
      }
      float sol = solve25(own, sbase, row);
      if (row < 24) b1s[row][fs] += sol;
    }
    __syncthreads();
  }

  // ---- final: ignorm([b0,b1], -0.5) @ B2MC_T ----
  if (tid < TF) {
    const int f = tid;
    float K = 1.f / sqrtf(b0s[f]);   // b0^gamma
    wfin[f][0] = 2.f * (1.f - K);
    for (int i = 1; i <= 24; ++i) wfin[f][i] = b1s[i - 1][f] * K;
  }
  __syncthreads();
  {
    const long obase = fbase * 25;
    const long OTOT = (long)T * 25;
    for (int t = tid; t < TF * 25; t += 256) {
      int f = t / 25, j = t - f * 25;
      float val = (j < 24) ? fmaf(0.42f, wfin[f][j + 1], wfin[f][j]) : wfin[f][24];
      long o = obase + t;
      if (o < OTOT) outg[o] = val;
    }
  }
}

extern "C" void kernel_launch(void* const* d_in, const int* in_sizes, int n_in,
                              void* d_out, int out_size, void* d_ws, size_t ws_size,
                              hipStream_t stream) {
  (void)d_ws; (void)ws_size; (void)n_in; (void)out_size;
  const float* x = (const float*)d_in[0];
  float* out = (float*)d_out;
  int T = in_sizes[0] / 257;

  hipLaunchKernelGGL(prepA, dim3(1), dim3(128), 0, stream);
  hipLaunchKernelGGL(prepB, dim3((257 * 49 + 255) / 256), dim3(256), 0, stream);
  hipLaunchKernelGGL(prepC, dim3((24 * 257 + 255) / 256), dim3(256), 0, stream);

  int nblk = (T + TF - 1) / TF;
  hipLaunchKernelGGL(mgc_main, dim3(nblk), dim3(256), 0, stream, x, out, T);
}

// Round 4
// 2127.176 us; speedup vs baseline: 1.0292x; 1.0292x over previous
//
#include <hip/hip_runtime.h>

#ifndef M_PI
#define M_PI 3.14159265358979323846
#endif

#define TF 16
#define NU (TF * 257)

// ---------------- precomputed operators (recomputed every launch; deterministic) ----------------
__device__ double g_tblc[512];
__device__ double g_tbls[512];
__device__ double g_CFP[49 * 512];   // cft(511,48,+0.42): [j 0..48][n 0..511]
__device__ double g_CFC[512 * 25];   // cft(24,511,-0.42): [n 0..511][m 0..24]
__device__ float2 g_g2[257 * 49];    // (Gc, Gs) [k][j]
__device__ __align__(16) float2 g_M4[257 * 12 * 2];   // [k][mp]: (Mcr[2mp],Mci[2mp]),(Mcr[2mp+1],Mci[2mp+1])
__device__ __align__(16) float g_PK[257 * 16 * 12];   // per (k,jg): c0,s0,c16,s16, cq1,sq1,cq17,sq17, cq33,sq33, 0,0

// systolic wavefront computation of the two cft recurrence matrices (fp64), plus trig tables
__global__ void prepA() {
  const int tid = threadIdx.x;
  const int w = tid >> 6;
  const int lane = tid & 63;
  if (w == 0) {
    const double a = 0.42, beta = 1.0 - a * a;
    double v1 = 0.0, v2 = 0.0;
    for (int s = 0; s < 49 + 512; ++s) {
      double up1 = __shfl_up(v1, 1);
      double up2 = __shfl_up(v2, 1);
      int j = s - lane;
      double val;
      if (lane == 0)      val = (j == 0) ? 1.0 : 0.0;
      else if (lane == 1) val = (j < 1) ? 0.0 : ((j == 1) ? beta : v1 * a);
      else                val = (j < 1) ? 0.0 : (up2 + a * (v1 - up1));
      if (lane < 49 && j >= 0 && j < 512) g_CFP[lane * 512 + j] = val;
      v2 = v1; v1 = val;
    }
  } else if (w == 1) {
    const double a = -0.42, beta = 1.0 - a * a;
    double c1 = (lane >= 1) ? pow(a, (double)(lane - 1)) * beta : 0.0;
    double v1 = 0.0, v2 = 0.0;
    for (int s = 0; s < 512 + 25; ++s) {
      double up1 = __shfl_up(v1, 1);
      double up2 = __shfl_up(v2, 1);
      int i = s - lane;
      double val;
      if (lane == 0) val = (i == 0) ? 1.0 : 0.0;
      else if (i < 1) val = 0.0;
      else if (i == 1) val = c1;
      else val = up2 + a * (up1 - v1);
      if (lane < 25 && i >= 0 && i < 512) g_CFC[i * 25 + lane] = val;
      v2 = v1; v1 = val;
    }
  }
  for (int t = tid; t < 512; t += blockDim.x) {
    double th = (2.0 * M_PI * (double)t) / 512.0;
    g_tblc[t] = cos(th);
    g_tbls[t] = sin(th);
  }
}

__global__ void prepB() {
  int idx = blockIdx.x * 256 + threadIdx.x;
  if (idx >= 257 * 49) return;
  int k = idx / 49, j = idx - k * 49;
  double ac = 0.0, as = 0.0;
  for (int n = 0; n < 512; ++n) {
    double wv = g_CFP[j * 512 + n];
    int t = (k * n) & 511;
    ac += g_tblc[t] * wv;
    as += g_tbls[t] * wv;
  }
  bool edge = (k == 0) || (k == 256);
  float gc = (float)((edge ? 1.0 : 2.0) / 512.0 * ac);
  float gs = edge ? 0.f : (float)(-2.0 / 512.0 * as);
  g_g2[idx] = make_float2(gc, gs);
}

__global__ void prepC() {
  int idx = blockIdx.x * 256 + threadIdx.x;
  if (idx >= 24 * 257) return;
  int m = idx / 257, k = idx - m * 257;
  double ar = 0.0, ai = 0.0;
  for (int n = 0; n < 512; ++n) {
    double wv = g_CFC[n * 25 + (m + 1)];
    int t = (k * n) & 511;
    ar += g_tblc[t] * wv;
    ai -= g_tbls[t] * wv;
  }
  g_M4[(k * 12 + (m >> 1)) * 2 + (m & 1)] = make_float2((float)ar, (float)ai);
}

__global__ void prepD() {
  int idx = blockIdx.x * 256 + threadIdx.x;
  if (idx >= 257 * 16) return;
  int k = idx >> 4, jg = idx & 15;
  float* o = g_PK + idx * 12;
  const float2* G = g_g2 + k * 49;
  float2 a0 = G[jg];
  float2 a1 = (jg < 9) ? G[jg + 16] : make_float2(0.f, 0.f);
  float2 q1 = G[jg + 1];
  float2 q2 = G[jg + 17];
  float2 q3 = G[jg + 33];
  o[0] = a0.x; o[1] = a0.y; o[2] = a1.x; o[3] = a1.y;
  o[4] = q1.x; o[5] = q1.y; o[6] = q2.x; o[7] = q2.y;
  o[8] = q3.x; o[9] = q3.y; o[10] = 0.f; o[11] = 0.f;
}

// ---------------- dual register-resident 24x24 GE (pivotless), 2 systems per 32-lane half ----------------
__device__ __forceinline__ void solve25x2(float (&oa)[25], float (&ob)[25],
                                          int base, int row, float& sa, float& sb) {
#pragma unroll
  for (int c = 0; c < 24; ++c) {
    float pa = __shfl(oa[c], base + c, 64);
    float pb = __shfl(ob[c], base + c, 64);
    float fa = oa[c] * __builtin_amdgcn_rcpf(pa);
    float fb = ob[c] * __builtin_amdgcn_rcpf(pb);
    bool act = (row > c) && (row < 24);
#pragma unroll
    for (int j = c + 1; j <= 24; ++j) {
      float ra = __shfl(oa[j], base + c, 64);
      float rb = __shfl(ob[j], base + c, 64);
      if (act) {
        oa[j] = fmaf(-fa, ra, oa[j]);
        ob[j] = fmaf(-fb, rb, ob[j]);
      }
    }
  }
  float acca = 0.f, accb = 0.f;
  sa = 0.f; sb = 0.f;
#pragma unroll
  for (int c = 23; c >= 0; --c) {
    float xa = __shfl((oa[24] - acca) * __builtin_amdgcn_rcpf(oa[c]), base + c, 64);
    float xb = __shfl((ob[24] - accb) * __builtin_amdgcn_rcpf(ob[c]), base + c, 64);
    if (row == c) { sa = xa; sb = xb; }
    if (row < c) { acca = fmaf(oa[c], xa, acca); accb = fmaf(ob[c], xb, accb); }
  }
}

__global__ __launch_bounds__(256, 4) void mgc_main(const float* __restrict__ xg,
                                                   float* __restrict__ outg,
                                                   int T) {
  __shared__ __align__(16) float2 U[NU];          // (Xr, Yi) fp32 per (frame, k)
  __shared__ __align__(16) float pqr[TF][98];     // p0[0..24] | q0[1..48]@[25..72] | r[0..24]@[73..97]
  __shared__ __align__(16) float b1s[24][TF];
  __shared__ float b0s[TF];                       // eps (final iter)

  const int tid = threadIdx.x;
  const long fbase = (long)blockIdx.x * TF;

  const int fP = tid >> 4;
  const int jg = tid & 15;
  const int lane = tid & 63;
  const int wv = tid >> 6;
  const int sbase = lane & 32;
  const int row = lane & 31;
  const int fA = 4 * wv + (lane >> 5);
  const int fB = fA + 2;

  long frow = fbase + fP;
  if (frow >= T) frow = T - 1;
  const float* xf = xg + frow * 257;

  // ---- stage A: p0 = x @ Gc (only 25 outputs needed) ----
  {
    float aP0 = 0.f, aP1 = 0.f;
    const float* gb = g_PK + jg * 12;
#pragma unroll 2
    for (int k = 0; k < 257; ++k) {
      float xv = xf[k];
      float4 A = *(const float4*)(gb + k * 192);
      aP0 = fmaf(xv, A.x, aP0);
      aP1 = fmaf(xv, A.z, aP1);
    }
    float* P = &pqr[fP][0];
    P[jg] = aP0;
    if (jg < 9) P[16 + jg] = aP1;
  }
  __syncthreads();

  // ---- stage A solve: Toeplitz(p') b1 = p0[1:] (PT stencil folded into setup) ----
  {
    float ownA[25], ownB[25];
    {
      const float* P = &pqr[fA][0];
#pragma unroll
      for (int j = 0; j < 25; ++j) ownA[j] = 1.f;
      if (row < 24) {
#pragma unroll
        for (int j = 0; j < 24; ++j) {
          int d = row > j ? row - j : j - row;
          ownA[j] = (d == 0) ? fmaf(0.84f, P[1], 0.8236f * P[0])
                             : fmaf(0.42f, P[d + 1], P[d]);
        }
        ownA[24] = P[row + 1];
      }
    }
    {
      const float* P = &pqr[fB][0];
#pragma unroll
      for (int j = 0; j < 25; ++j) ownB[j] = 1.f;
      if (row < 24) {
#pragma unroll
        for (int j = 0; j < 24; ++j) {
          int d = row > j ? row - j : j - row;
          ownB[j] = (d == 0) ? fmaf(0.84f, P[1], 0.8236f * P[0])
                             : fmaf(0.42f, P[d + 1], P[d]);
        }
        ownB[24] = P[row + 1];
      }
    }
    float sA, sB;
    solve25x2(ownA, ownB, sbase, row, sA, sB);
    if (row < 24) { b1s[row][fA] = sA; b1s[row][fB] = sB; }
  }
  __syncthreads();

  // ---- stage A chain: ignorm/B2MC/gnorm/gc2gc/ignorm/MC2B/gnorm (1 thread / frame, LDS scratch) ----
  if (tid < TF) {
    float* P = &pqr[tid][0];
    float s = 0.f;
    for (int m = 0; m < 24; ++m) s = fmaf(P[m + 1], b1s[m][tid], s);
    float K = 1.f / sqrtf(P[0] - s);          // 1/b0
    float* c2 = P + 25;
    c2[0] = 1.f - K;                          // ignorm(b,-1)
    for (int i = 1; i <= 24; ++i) c2[i] = b1s[i - 1][tid] * K;
    for (int j = 0; j < 24; ++j) P[j] = fmaf(0.42f, c2[j + 1], c2[j]);  // @B2MC_T
    P[24] = c2[24];
    float iz = 1.f / (1.f - P[0]);            // gnorm(c,-1)
    P[0] = iz;
    for (int i = 1; i <= 24; ++i) P[i] *= iz;
    c2[0] = P[0]; c2[1] = P[1];               // gc2gc(-1 -> -0.5)
    for (int i = 2; i <= 24; ++i) {
      float s2 = 0.f, s1 = 0.f;
      for (int kk = 1; kk < i; ++kk) {
        float cc = P[kk] * c2[i - kk];
        s2 += (float)kk * cc;
        s1 += (float)(i - kk) * cc;
      }
      c2[i] = P[i] + fmaf(-0.5f, s2, s1) / (float)i;
    }
    float K2 = 1.f / sqrtf(c2[0]);            // ignorm(c2, -0.5)
    c2[0] = 2.f * (1.f - K2);
    for (int i = 1; i <= 24; ++i) c2[i] *= K2;
    P[24] = c2[24];                           // @MC2B_T (backward)
    for (int j = 23; j >= 0; --j) P[j] = fmaf(-0.42f, P[j + 1], c2[j]);
    float iz2 = 1.f / fmaf(-0.5f, P[0], 1.f); // gnorm(v,-0.5)[1:]
    for (int m = 0; m < 24; ++m) b1s[m][tid] = P[m + 1] * iz2;
  }
  __syncthreads();

  // ---- 6 Newton iterations ----
#pragma unroll 1
  for (int itn = 0; itn < 6; ++itn) {
    // P1: Xr/Yi spectra (16-frame register blocking), fp32
    for (int k = tid; k < 257; k += 256) {
      float cr[TF], ci[TF];
#pragma unroll
      for (int f = 0; f < TF; ++f) { cr[f] = 0.f; ci[f] = 0.f; }
      const float4* M4 = (const float4*)g_M4;
#pragma unroll 2
      for (int mp = 0; mp < 12; ++mp) {
        float4 mm = M4[k * 12 + mp];
        const float4* ba4 = (const float4*)(&b1s[2 * mp][0]);
        const float4* bb4 = (const float4*)(&b1s[2 * mp + 1][0]);
        float4 a0 = ba4[0], a1 = ba4[1], a2 = ba4[2], a3 = ba4[3];
        float4 c0 = bb4[0], c1 = bb4[1], c2 = bb4[2], c3 = bb4[3];
        float av[TF] = {a0.x, a0.y, a0.z, a0.w, a1.x, a1.y, a1.z, a1.w,
                        a2.x, a2.y, a2.z, a2.w, a3.x, a3.y, a3.z, a3.w};
        float bv[TF] = {c0.x, c0.y, c0.z, c0.w, c1.x, c1.y, c1.z, c1.w,
                        c2.x, c2.y, c2.z, c2.w, c3.x, c3.y, c3.z, c3.w};
#pragma unroll
        for (int f = 0; f < TF; ++f) {
          cr[f] = fmaf(bv[f], mm.z, fmaf(av[f], mm.x, cr[f]));
          ci[f] = fmaf(bv[f], mm.w, fmaf(av[f], mm.y, ci[f]));
        }
      }
#pragma unroll
      for (int f = 0; f < TF; ++f)
        U[f * 257 + k] = make_float2(fmaf(-0.5f, cr[f], 1.f), -0.5f * ci[f]);
    }
    __syncthreads();

    // P2: 5-channel contraction (ps = x*D, qs = x for gamma = -1/2), 98 outputs
    {
      float aP0 = 0.f, aP1 = 0.f, aQ0 = 0.f, aQ1 = 0.f, aQ2 = 0.f, aR0 = 0.f, aR1 = 0.f;
      const float2* uf = U + fP * 257;
      const float* gb = g_PK + jg * 12;
#pragma unroll 2
      for (int k = 0; k < 257; ++k) {
        float xv = xf[k];
        float2 cc = uf[k];
        float Xr = cc.x, Yi = cc.y;
        float u = xv * Xr, v = xv * Yi;
        float a = u * Xr, b = v * Yi;
        float xD = a + b, zqr = a - b;
        float zqi = fmaf(u, Yi, v * Xr);
        float zrr = xD * Xr, zri = xD * Yi;
        const float* g = gb + k * 192;
        float4 A = *(const float4*)g;
        float4 B = *(const float4*)(g + 4);
        float2 C = *(const float2*)(g + 8);
        aP0 = fmaf(xD, A.x, aP0);
        aP1 = fmaf(xD, A.z, aP1);
        aR0 = fmaf(zrr, A.x, fmaf(zri, A.y, aR0));
        aR1 = fmaf(zrr, A.z, fmaf(zri, A.w, aR1));
        aQ0 = fmaf(zqr, B.x, fmaf(zqi, B.y, aQ0));
        aQ1 = fmaf(zqr, B.z, fmaf(zqi, B.w, aQ1));
        aQ2 = fmaf(zqr, C.x, fmaf(zqi, C.y, aQ2));
      }
      float* P = &pqr[fP][0];
      P[jg] = aP0;
      if (jg < 9) P[16 + jg] = aP1;
      P[25 + jg] = aQ0;
      P[41 + jg] = aQ1;
      P[57 + jg] = aQ2;
      P[73 + jg] = aR0;
      if (jg < 9) P[89 + jg] = aR1;
    }
    __syncthreads();

    // P4: (R + Q) d = r[1:], b1 += d   (PT/QT stencils folded into setup)
    {
      float ownA[25], ownB[25];
      {
        const float* P = &pqr[fA][0];
#pragma unroll
        for (int j = 0; j < 25; ++j) ownA[j] = 1.f;
        if (row < 24) {
#pragma unroll
          for (int j = 0; j < 24; ++j) {
            int d = row > j ? row - j : j - row;
            float pp = (d == 0) ? fmaf(0.84f, P[1], 0.8236f * P[0])
                                : fmaf(0.42f, P[d + 1], P[d]);
            float qq = fmaf(0.42f, P[25 + row + j], P[26 + row + j]);
            ownA[j] = fmaf(0.5f, qq, pp);
          }
          ownA[24] = P[74 + row];
        }
      }
      {
        const float* P = &pqr[fB][0];
#pragma unroll
        for (int j = 0; j < 25; ++j) ownB[j] = 1.f;
        if (row < 24) {
#pragma unroll
          for (int j = 0; j < 24; ++j) {
            int d = row > j ? row - j : j - row;
            float pp = (d == 0) ? fmaf(0.84f, P[1], 0.8236f * P[0])
                                : fmaf(0.42f, P[d + 1], P[d]);
            float qq = fmaf(0.42f, P[25 + row + j], P[26 + row + j]);
            ownB[j] = fmaf(0.5f, qq, pp);
          }
          ownB[24] = P[74 + row];
        }
      }
      float rA = ownA[24], rB = ownB[24];
      float bA = (row < 24) ? b1s[row][fA] : 0.f;
      float bB = (row < 24) ? b1s[row][fB] : 0.f;
      float sA, sB;
      solve25x2(ownA, ownB, sbase, row, sA, sB);
      if (itn == 5) {  // eps uses pre-update b1 of the final iteration only
        float pa = (row < 24) ? rA * bA : 0.f;
        float pb = (row < 24) ? rB * bB : 0.f;
#pragma unroll
        for (int mask = 16; mask >= 1; mask >>= 1) {
          pa += __shfl_xor(pa, mask, 64);
          pb += __shfl_xor(pb, mask, 64);
        }
        if (row == 0) {
          b0s[fA] = pqr[fA][73] - 0.5f * pa;
          b0s[fB] = pqr[fB][73] - 0.5f * pb;
        }
      }
      if (row < 24) { b1s[row][fA] += sA; b1s[row][fB] += sB; }
    }
    __syncthreads();
  }

  // ---- final: ignorm([b0,b1], -0.5) @ B2MC_T, written directly ----
  {
    const long OTOT = (long)T * 25;
    for (int t = tid; t < TF * 25; t += 256) {
      int f = t / 25, j = t - f * 25;
      float K = 1.f / sqrtf(sqrtf(b0s[f]));   // eps^(-1/4) = b0^gamma
      float val;
      if (j == 0)      val = fmaf(0.42f * K, b1s[0][f], 2.f * (1.f - K));
      else if (j < 24) val = K * fmaf(0.42f, b1s[j][f], b1s[j - 1][f]);
      else             val = K * b1s[23][f];
      long o = fbase * 25 + t;
      if (o < OTOT) outg[o] = val;
    }
  }
}

extern "C" void kernel_launch(void* const* d_in, const int* in_sizes, int n_in,
                              void* d_out, int out_size, void* d_ws, size_t ws_size,
                              hipStream_t stream) {
  (void)d_ws; (void)ws_size; (void)n_in; (void)out_size;
  const float* x = (const float*)d_in[0];
  float* out = (float*)d_out;
  int T = in_sizes[0] / 257;

  hipLaunchKernelGGL(prepA, dim3(1), dim3(128), 0, stream);
  hipLaunchKernelGGL(prepB, dim3((257 * 49 + 255) / 256), dim3(256), 0, stream);
  hipLaunchKernelGGL(prepC, dim3((24 * 257 + 255) / 256), dim3(256), 0, stream);
  hipLaunchKernelGGL(prepD, dim3((257 * 16 + 255) / 256), dim3(256), 0, stream);

  int nblk = (T + TF - 1) / TF;
  hipLaunchKernelGGL(mgc_main, dim3(nblk), dim3(256), 0, stream, x, out, T);
}